// Round 10
// baseline (587.952 us; speedup 1.0000x reference)
//
#include <hip/hip_runtime.h>
#include <hip/hip_bf16.h>
#include <math.h>

// Problem constants
#define BB 128
#define TT 256
#define DV 1024
#define DA 128
#define HH 128
#define DF 512
#define KC 7
#define MM (BB*TT)   // 32768 rows

typedef __attribute__((ext_vector_type(8))) short    short8v;  // 8x16b LDS stage
typedef __attribute__((ext_vector_type(8))) _Float16 half8v;   // MFMA A/B frag
typedef __attribute__((ext_vector_type(4))) float    float4v;  // MFMA acc

__device__ __forceinline__ float gelu_exact(float v) {
    return 0.5f * v * (1.0f + erff(v * 0.70710678118654752f));
}
__device__ __forceinline__ ushort f2h(float f) {   // RNE fp32->fp16
    _Float16 h = (_Float16)f;
    return __builtin_bit_cast(ushort, h);
}
__device__ __forceinline__ float h2f(ushort u) {
    _Float16 h = __builtin_bit_cast(_Float16, u);
    return (float)h;
}

// ---------------------------------------------------------------------------
// Weight prepass: W[K][N] fp32 (row-major) -> Wt [N][K] fp16.
// grid (N/64, K/64), 256 threads, LDS-tiled transpose.
// ---------------------------------------------------------------------------
__global__ __launch_bounds__(256) void wconv_kernel(const float* __restrict__ W,
                                                    ushort* __restrict__ Th,
                                                    int K, int N)
{
    __shared__ float sT[64][65];
    const int n0 = blockIdx.x * 64, k0 = blockIdx.y * 64;
    const int t = threadIdx.x;
    const int kk = t >> 4, n4 = (t & 15) * 4;
#pragma unroll
    for (int i = 0; i < 4; ++i) {
        float4 f = *(const float4*)(W + (size_t)(k0 + kk + i * 16) * N + n0 + n4);
        sT[kk + i * 16][n4 + 0] = f.x;
        sT[kk + i * 16][n4 + 1] = f.y;
        sT[kk + i * 16][n4 + 2] = f.z;
        sT[kk + i * 16][n4 + 3] = f.w;
    }
    __syncthreads();
    const int n = t >> 2, kq = (t & 3) * 16;
    ushort hh[16];
#pragma unroll
    for (int j = 0; j < 16; ++j) hh[j] = f2h(sT[kq + j][n]);
    ushort* dh = Th + (size_t)(n0 + n) * K + k0 + kq;
#pragma unroll
    for (int j = 0; j < 16; j += 4)
        *(ushort4*)(dh + j) = make_ushort4(hh[j], hh[j+1], hh[j+2], hh[j+3]);
}

// ---------------------------------------------------------------------------
// Bias concat: dst[0:128) = a, dst[128:256) = b.
// ---------------------------------------------------------------------------
__global__ __launch_bounds__(256) void bcat_kernel(const float* __restrict__ a,
                                                   const float* __restrict__ b,
                                                   float* __restrict__ dst)
{
    const int t = threadIdx.x;
    dst[t] = (t < 128) ? a[t] : b[t - 128];
}

// ---------------------------------------------------------------------------
// fp16 MFMA GEMM.  C[M,N] = A[M,K] @ W[K,N] + bias.
// BM: 128 (4 waves 2x2, 64x64/wave) or 64 (4 waves 2x2, 32x64/wave).
// A_F32: 1 -> A fp32, convert to fp16 while staging; 0 -> A already fp16.
// B: fp16 [N][K] row-major (K contiguous).
// OUT: 0 -> fp32 C ; 1 -> gelu + fp16 C ; 2 -> fp16 C.
// BK=32, 16x16x32 MFMA.  LDS [kgrp][row][8] -> conflict-light ds_read_b128.
// Epilogue stages C tile through the (reused) 16KB LDS for coalesced 16B
// stores (the round-9 top dispatch was store-bound on 2B scattered stores).
// XCD-aware bijective block swizzle: contiguous by-chunks per XCD -> A-tile
// L2 reuse across the bx blocks that share it (requires nwg % 8 == 0).
// ---------------------------------------------------------------------------
template<int BM, int A_F32, int OUT>
__global__ __launch_bounds__(256) void mgemm(const void* __restrict__ Av, int lda,
                                             const ushort* __restrict__ Bt,
                                             const float* __restrict__ bias,
                                             void* __restrict__ Cv,
                                             int N, int K)
{
    constexpr int MF = BM / 32;              // m-fragments per wave
    __shared__ __align__(16) ushort smem[8192];           // 16 KB
    auto Ah = (ushort (*)[BM][8])(smem);                  // [4][BM][8]
    auto Bh = (ushort (*)[128][8])(smem + 4 * BM * 8);    // [4][128][8]

    // XCD swizzle (all launches have nwg % 8 == 0)
    const int nwg = gridDim.x * gridDim.y;
    const int hid = blockIdx.y * gridDim.x + blockIdx.x;
    const int d   = (hid & 7) * (nwg >> 3) + (hid >> 3);
    const int bx  = d % gridDim.x, by = d / gridDim.x;

    const int tid = threadIdx.x;
    const int l = tid & 63;
    const int w = tid >> 6;
    const int wrow = (w >> 1) * (MF * 16), wcol = (w & 1) * 64;
    const int m0 = by * BM, n0 = bx * 128;

    float4v acc[MF][4];
#pragma unroll
    for (int m = 0; m < MF; ++m)
#pragma unroll
        for (int n = 0; n < 4; ++n) acc[m][n] = (float4v){0.f, 0.f, 0.f, 0.f};

    for (int k0 = 0; k0 < K; k0 += 32) {
        __syncthreads();
        // ---- stage A ----
        if (A_F32) {
            if (BM == 128) {
                const int srow = tid >> 1, kh = (tid & 1) * 16;
                const float* Ap = (const float*)Av + (size_t)(m0 + srow) * lda + k0 + kh;
#pragma unroll
                for (int i = 0; i < 4; ++i) {
                    float4 f = *(const float4*)(Ap + i * 4);
                    *(ushort4*)&Ah[(kh >> 3) + (i >> 1)][srow][(i & 1) * 4] =
                        make_ushort4(f2h(f.x), f2h(f.y), f2h(f.z), f2h(f.w));
                }
            } else {
                const int srow = tid >> 2, ko = (tid & 3) * 8;
                const float* Ap = (const float*)Av + (size_t)(m0 + srow) * lda + k0 + ko;
#pragma unroll
                for (int i = 0; i < 2; ++i) {
                    float4 f = *(const float4*)(Ap + i * 4);
                    *(ushort4*)&Ah[ko >> 3][srow][i * 4] =
                        make_ushort4(f2h(f.x), f2h(f.y), f2h(f.z), f2h(f.w));
                }
            }
        } else {
            if (BM == 128) {
                const int srow = tid >> 1, kh = (tid & 1) * 16;
                const ushort* Ap = (const ushort*)Av + (size_t)(m0 + srow) * lda + k0 + kh;
                *(short8v*)&Ah[(kh >> 3) + 0][srow][0] = *(const short8v*)(Ap + 0);
                *(short8v*)&Ah[(kh >> 3) + 1][srow][0] = *(const short8v*)(Ap + 8);
            } else {
                const int srow = tid >> 2, ko = (tid & 3) * 8;
                const ushort* Ap = (const ushort*)Av + (size_t)(m0 + srow) * lda + k0 + ko;
                *(short8v*)&Ah[ko >> 3][srow][0] = *(const short8v*)Ap;
            }
        }
        // ---- stage B ----
        {
            const int srow = tid >> 1, kh = (tid & 1) * 16;
            const ushort* Bp = Bt + (size_t)(n0 + srow) * K + k0 + kh;
            *(short8v*)&Bh[(kh >> 3) + 0][srow][0] = *(const short8v*)(Bp + 0);
            *(short8v*)&Bh[(kh >> 3) + 1][srow][0] = *(const short8v*)(Bp + 8);
        }
        __syncthreads();

        const int g = l >> 4, lr = l & 15;
        half8v af[MF], bf_[4];
#pragma unroll
        for (int m = 0; m < MF; ++m)
            af[m] = *(const half8v*)&Ah[g][wrow + m * 16 + lr][0];
#pragma unroll
        for (int n = 0; n < 4; ++n)
            bf_[n] = *(const half8v*)&Bh[g][wcol + n * 16 + lr][0];
#pragma unroll
        for (int m = 0; m < MF; ++m)
#pragma unroll
            for (int n = 0; n < 4; ++n)
                acc[m][n] = __builtin_amdgcn_mfma_f32_16x16x32_f16(af[m], bf_[n], acc[m][n], 0, 0, 0);
    }

    // ---- epilogue: C/D frag (col=lane&15, row=(lane>>4)*4+reg) -> LDS -> 16B stores
    {
        const int g2 = l >> 4, lr = l & 15;
        constexpr int RPP = (OUT == 0) ? 32 : 64;   // rows per pass (16KB LDS)
#pragma unroll
        for (int row0 = 0; row0 < BM; row0 += RPP) {
            __syncthreads();   // previous pass stores / K-loop LDS reads done
#pragma unroll
            for (int m = 0; m < MF; ++m) {
                const int rbase = wrow + m * 16 + g2 * 4;
                if (rbase >= row0 && rbase < row0 + RPP) {
#pragma unroll
                    for (int n = 0; n < 4; ++n) {
                        const int col = wcol + n * 16 + lr;
                        const float bv = bias[n0 + col];
#pragma unroll
                        for (int r = 0; r < 4; ++r) {
                            const float o = acc[m][n][r] + bv;
                            const int lrow = rbase + r - row0;
                            if (OUT == 0)      ((float*)smem)[lrow * 128 + col] = o;
                            else if (OUT == 1) smem[lrow * 128 + col] = f2h(gelu_exact(o));
                            else               smem[lrow * 128 + col] = f2h(o);
                        }
                    }
                }
            }
            __syncthreads();
            if (OUT == 0) {
#pragma unroll
                for (int it = 0; it < (RPP * 128) / (4 * 256); ++it) {
                    const int u = tid + it * 256;
                    const int rr = u >> 5, cc = (u & 31) * 4;
                    *(float4*)&((float*)Cv)[(size_t)(m0 + row0 + rr) * N + n0 + cc] =
                        *(float4*)&((float*)smem)[rr * 128 + cc];
                }
            } else {
#pragma unroll
                for (int it = 0; it < (RPP * 128) / (8 * 256); ++it) {
                    const int u = tid + it * 256;
                    const int rr = u >> 4, cc = (u & 15) * 8;
                    *(short8v*)&((ushort*)Cv)[(size_t)(m0 + row0 + rr) * N + n0 + cc] =
                        *(short8v*)&smem[rr * 128 + cc];
                }
            }
        }
    }
}

// ---------------------------------------------------------------------------
// Attention phase 1: S[b,q,k] = (Q.K) * scale + adj(q,k)
// K now lives in the fused kv buffer: row stride 256, cols 0..127.
// ---------------------------------------------------------------------------
__global__ __launch_bounds__(256) void scores_kernel(const float* __restrict__ q,
                                                     const float* __restrict__ kv,
                                                     float* __restrict__ S)
{
    const int kh = blockIdx.x;
    const int qh = blockIdx.y;
    const int b  = blockIdx.z;
    const int tid = threadIdx.x;
    const int tr = tid >> 4;
    const int tc = tid & 15;

    __shared__ float sA[32][68];
    __shared__ float sB[32][132];

    const float* Ab = q + ((size_t)b * TT + qh * 64) * HH;
    const float* Bb = kv + ((size_t)b * TT + kh * 128) * 256;   // k half

    float acc[4][8];
#pragma unroll
    for (int i = 0; i < 4; ++i)
#pragma unroll
        for (int j = 0; j < 8; ++j) acc[i][j] = 0.0f;

    for (int k0 = 0; k0 < 128; k0 += 32) {
        __syncthreads();
#pragma unroll
        for (int ll = 0; ll < 2; ++ll) {
            int f = tid + ll * 256;
            int row = f >> 3, c4 = f & 7;
            float4 val = *(const float4*)(Ab + (size_t)row * HH + k0 + c4 * 4);
            sA[c4 * 4 + 0][row] = val.x;
            sA[c4 * 4 + 1][row] = val.y;
            sA[c4 * 4 + 2][row] = val.z;
            sA[c4 * 4 + 3][row] = val.w;
        }
#pragma unroll
        for (int ll = 0; ll < 4; ++ll) {
            int f = tid + ll * 256;
            int row = f >> 3, c4 = f & 7;
            float4 val = *(const float4*)(Bb + (size_t)row * 256 + k0 + c4 * 4);
            sB[c4 * 4 + 0][row] = val.x;
            sB[c4 * 4 + 1][row] = val.y;
            sB[c4 * 4 + 2][row] = val.z;
            sB[c4 * 4 + 3][row] = val.w;
        }
        __syncthreads();
#pragma unroll
        for (int kk = 0; kk < 32; ++kk) {
            float4 a4 = *(const float4*)&sA[kk][tr * 4];
            float4 b0 = *(const float4*)&sB[kk][tc * 8];
            float4 b1 = *(const float4*)&sB[kk][tc * 8 + 4];
            float a[4]  = {a4.x, a4.y, a4.z, a4.w};
            float bb[8] = {b0.x, b0.y, b0.z, b0.w, b1.x, b1.y, b1.z, b1.w};
#pragma unroll
            for (int i = 0; i < 4; ++i)
#pragma unroll
                for (int j = 0; j < 8; ++j) acc[i][j] += a[i] * bb[j];
        }
    }

    const float scale = 0.088388347648318447f;   // 1/sqrt(128)
    const float inv_e = 0.36787944117144233f;    // 1/e
#pragma unroll
    for (int i = 0; i < 4; ++i) {
        int rq = qh * 64 + tr * 4 + i;
        float* srow = S + ((size_t)b * TT + rq) * TT + kh * 128 + tc * 8;
        float o[8];
#pragma unroll
        for (int j = 0; j < 8; ++j) {
            int ck = kh * 128 + tc * 8 + j;
            float adj = expf(-fabsf((float)(rq - ck)) * inv_e);
            o[j] = acc[i][j] * scale + adj;
        }
        *(float4*)srow       = make_float4(o[0], o[1], o[2], o[3]);
        *(float4*)(srow + 4) = make_float4(o[4], o[5], o[6], o[7]);
    }
}

// ---------------------------------------------------------------------------
// Attention phase 2: row softmax (in place), one wave per 256-el row.
// ---------------------------------------------------------------------------
__global__ __launch_bounds__(256) void softmax_kernel(float* __restrict__ S)
{
    const int row  = blockIdx.x * 4 + (threadIdx.x >> 6);
    const int lane = threadIdx.x & 63;
    float* p = S + (size_t)row * TT + lane * 4;
    float4 v = *(float4*)p;
    float m = fmaxf(fmaxf(v.x, v.y), fmaxf(v.z, v.w));
#pragma unroll
    for (int mask = 1; mask < 64; mask <<= 1) m = fmaxf(m, __shfl_xor(m, mask));
    float e0 = expf(v.x - m), e1 = expf(v.y - m), e2 = expf(v.z - m), e3 = expf(v.w - m);
    float s = e0 + e1 + e2 + e3;
#pragma unroll
    for (int mask = 1; mask < 64; mask <<= 1) s += __shfl_xor(s, mask);
    float inv = 1.0f / s;
    *(float4*)p = make_float4(e0 * inv, e1 * inv, e2 * inv, e3 * inv);
}

// ---------------------------------------------------------------------------
// Attention phase 3: ctx = S @ V (V = kv cols 128..255), output fp16.
// ---------------------------------------------------------------------------
__global__ __launch_bounds__(256) void pv_kernel(const float* __restrict__ S,
                                                 const float* __restrict__ kv,
                                                 ushort* __restrict__ ctx)
{
    const int qh = blockIdx.x;
    const int b  = blockIdx.y;
    const int tid = threadIdx.x;
    const int tr = tid >> 4;
    const int tc = tid & 15;

    __shared__ float sA[32][68];
    __shared__ float sB[32][132];

    const float* Ab = S + ((size_t)b * TT + qh * 64) * TT;
    const float* Bb = kv + (size_t)b * TT * 256 + 128;   // v half

    float acc[4][8];
#pragma unroll
    for (int i = 0; i < 4; ++i)
#pragma unroll
        for (int j = 0; j < 8; ++j) acc[i][j] = 0.0f;

    for (int k0 = 0; k0 < 256; k0 += 32) {
        __syncthreads();
#pragma unroll
        for (int ll = 0; ll < 2; ++ll) {
            int f = tid + ll * 256;
            int row = f >> 3, c4 = f & 7;
            float4 val = *(const float4*)(Ab + (size_t)row * TT + k0 + c4 * 4);
            sA[c4 * 4 + 0][row] = val.x;
            sA[c4 * 4 + 1][row] = val.y;
            sA[c4 * 4 + 2][row] = val.z;
            sA[c4 * 4 + 3][row] = val.w;
        }
#pragma unroll
        for (int ll = 0; ll < 4; ++ll) {
            int f = tid + ll * 256;
            int row = f >> 5, c4 = f & 31;
            float4 val = *(const float4*)(Bb + (size_t)(k0 + row) * 256 + c4 * 4);
            *(float4*)&sB[row][c4 * 4] = val;
        }
        __syncthreads();
#pragma unroll
        for (int kk = 0; kk < 32; ++kk) {
            float4 a4 = *(const float4*)&sA[kk][tr * 4];
            float4 b0 = *(const float4*)&sB[kk][tc * 8];
            float4 b1 = *(const float4*)&sB[kk][tc * 8 + 4];
            float a[4]  = {a4.x, a4.y, a4.z, a4.w};
            float bb[8] = {b0.x, b0.y, b0.z, b0.w, b1.x, b1.y, b1.z, b1.w};
#pragma unroll
            for (int i = 0; i < 4; ++i)
#pragma unroll
                for (int j = 0; j < 8; ++j) acc[i][j] += a[i] * bb[j];
        }
    }

#pragma unroll
    for (int i = 0; i < 4; ++i) {
        ushort* crow = ctx + ((size_t)b * TT + qh * 64 + tr * 4 + i) * HH + tc * 8;
        *(ushort4*)crow       = make_ushort4(f2h(acc[i][0]), f2h(acc[i][1]),
                                             f2h(acc[i][2]), f2h(acc[i][3]));
        *(ushort4*)(crow + 4) = make_ushort4(f2h(acc[i][4]), f2h(acc[i][5]),
                                             f2h(acc[i][6]), f2h(acc[i][7]));
    }
}

// ---------------------------------------------------------------------------
// Residual + LayerNorm: h = LN(fv + ca16) * g + b -> fp16 (separate buffer).
// ---------------------------------------------------------------------------
__global__ __launch_bounds__(256) void resln_kernel(const float* __restrict__ x,
                                                    const ushort* __restrict__ ca16,
                                                    ushort* __restrict__ h16,
                                                    const float* __restrict__ gam,
                                                    const float* __restrict__ bet)
{
    const int row = blockIdx.x;
    const int tid = threadIdx.x;
    const float4 f = *(const float4*)(x + (size_t)row * 1152 + tid * 4);
    const ushort4 c4v = *(const ushort4*)(ca16 + (size_t)row * 1024 + tid * 4);
    float4 h;
    h.x = f.x + h2f(c4v.x); h.y = f.y + h2f(c4v.y);
    h.z = f.z + h2f(c4v.z); h.w = f.w + h2f(c4v.w);

    float s  = h.x + h.y + h.z + h.w;
    float ss = h.x * h.x + h.y * h.y + h.z * h.z + h.w * h.w;
#pragma unroll
    for (int m = 1; m < 64; m <<= 1) {
        s  += __shfl_xor(s, m);
        ss += __shfl_xor(ss, m);
    }
    __shared__ float red[8];
    if ((tid & 63) == 0) {
        red[tid >> 6]       = s;
        red[4 + (tid >> 6)] = ss;
    }
    __syncthreads();
    s  = red[0] + red[1] + red[2] + red[3];
    ss = red[4] + red[5] + red[6] + red[7];
    const float mean = s * (1.0f / 1024.0f);
    const float var  = ss * (1.0f / 1024.0f) - mean * mean;
    const float rstd = 1.0f / sqrtf(var + 1e-5f);

    const float4 g4 = *(const float4*)(gam + tid * 4);
    const float4 b4 = *(const float4*)(bet + tid * 4);
    ushort* hout = h16 + (size_t)row * 1024 + tid * 4;
    *(ushort4*)hout = make_ushort4(
        f2h((h.x - mean) * rstd * g4.x + b4.x),
        f2h((h.y - mean) * rstd * g4.y + b4.y),
        f2h((h.z - mean) * rstd * g4.z + b4.z),
        f2h((h.w - mean) * rstd * g4.w + b4.w));
}

// ---------------------------------------------------------------------------
// Causal conv (KC=7) + sigmoid.
// ---------------------------------------------------------------------------
__global__ __launch_bounds__(256) void conv_kernel(const float* __restrict__ h2,
                                                   const float* __restrict__ Wc,
                                                   const float* __restrict__ bcp,
                                                   float* __restrict__ out)
{
    const int t0 = blockIdx.x * 64;
    const int b  = blockIdx.y;
    const int tid = threadIdx.x;

    __shared__ float sw[896];
    __shared__ float sh[70][130];
    __shared__ float red[4][64];

    for (int i = tid; i < 896; i += 256) sw[i] = Wc[i];
    for (int f = tid; f < 70 * 32; f += 256) {
        int rr = f >> 5, c4 = f & 31;
        int trow = t0 - 6 + rr;
        float4 val = make_float4(0.f, 0.f, 0.f, 0.f);
        if (trow >= 0)
            val = *(const float4*)(h2 + ((size_t)b * TT + trow) * HH + c4 * 4);
        sh[rr][c4 * 4 + 0] = val.x;
        sh[rr][c4 * 4 + 1] = val.y;
        sh[rr][c4 * 4 + 2] = val.z;
        sh[rr][c4 * 4 + 3] = val.w;
    }
    __syncthreads();

    const int tt  = tid & 63;
    const int grp = tid >> 6;
    const int i0  = grp * 32;
    float acc = 0.0f;
    for (int j = 0; j < 7; ++j) {
        const int srow2 = tt + j;
#pragma unroll
        for (int i2 = 0; i2 < 16; ++i2) {
            float2 hv = *(const float2*)&sh[srow2][i0 + i2 * 2];
            acc += hv.x * sw[(i0 + i2 * 2) * 7 + j] + hv.y * sw[(i0 + i2 * 2 + 1) * 7 + j];
        }
    }
    red[grp][tt] = acc;
    __syncthreads();
    if (grp == 0) {
        float tot = red[0][tt] + red[1][tt] + red[2][tt] + red[3][tt] + bcp[0];
        out[(size_t)b * TT + t0 + tt] = 1.0f / (1.0f + expf(-tot));
    }
}

// ---------------------------------------------------------------------------
extern "C" void kernel_launch(void* const* d_in, const int* in_sizes, int n_in,
                              void* d_out, int out_size, void* d_ws, size_t ws_size,
                              hipStream_t stream)
{
    const float* x   = (const float*)d_in[0];
    const float* Wq  = (const float*)d_in[1];
    const float* bq  = (const float*)d_in[2];
    const float* Wk  = (const float*)d_in[3];
    const float* bk  = (const float*)d_in[4];
    const float* Wv  = (const float*)d_in[5];
    const float* bv  = (const float*)d_in[6];
    const float* Wo  = (const float*)d_in[7];
    const float* bo  = (const float*)d_in[8];
    const float* lng = (const float*)d_in[9];
    const float* lnb = (const float*)d_in[10];
    const float* W1  = (const float*)d_in[11];
    const float* b1  = (const float*)d_in[12];
    const float* W2  = (const float*)d_in[13];
    const float* b2  = (const float*)d_in[14];
    const float* Wc  = (const float*)d_in[15];
    const float* bc  = (const float*)d_in[16];
    float* out = (float*)d_out;
    char* wsb = (char*)d_ws;

    // ---- workspace map (peak 197.1 MB) ----
    ushort* WT   = (ushort*)wsb;                        // [0, 2.0M) fp16 weights [N][K]
    const size_t oWq  = 0;                              // 128x128
    const size_t oWkv = 16384;                          // 256x1024 (k rows 0-127, v 128-255)
    const size_t oWo  = 278528;                         // 1024x128
    const size_t oW1  = 409600;                         // 512x1024
    const size_t oW2  = 933888;                         // 128x512
    float*  bkv  = (float*)(wsb + 2097152);             // [2.0M, +1KB) concat bias
    float*  qb   = (float*)(wsb + 4194304);             // [4.2M, 21.0M) fp32 [MM][128]
    float*  kvb  = (float*)(wsb + 20971520);            // [21.0M, 54.5M) fp32 [MM][256]
    ushort* ctxb = (ushort*)(wsb + 54525952);           // [54.5M, 62.9M) fp16
    float*  Sbuf = (float*)(wsb + 62914560);            // [62.9M, 96.5M) fp32 scores
    ushort* ca16 = (ushort*)(wsb + 62914560);           // [62.9M, 130.0M) fp16 ca (after S dead)
    ushort* h16  = (ushort*)(wsb + 130023424);          // [130.0M, 197.1M) fp16 h
    ushort* hf   = (ushort*)(wsb + 4194304);            // reuse qb+kvb head (fp16, 33.5M)
    float*  h2   = (float*)(wsb + 37748736);            // reuse kvb tail (fp32, 16.8M)

    dim3 thr(256);
    // ---- weight transpose + fp16 convert prepass (grid = (N/64, K/64)) ----
    wconv_kernel<<<dim3(2, 2),  thr, 0, stream>>>(Wq, WT + oWq, 128, 128);
    wconv_kernel<<<dim3(2, 16), thr, 0, stream>>>(Wk, WT + oWkv, 1024, 128);
    wconv_kernel<<<dim3(2, 16), thr, 0, stream>>>(Wv, WT + oWkv + 128 * 1024, 1024, 128);
    wconv_kernel<<<dim3(16, 2), thr, 0, stream>>>(Wo, WT + oWo, 128, 1024);
    wconv_kernel<<<dim3(8, 16), thr, 0, stream>>>(W1, WT + oW1, 1024, 512);
    wconv_kernel<<<dim3(2, 8),  thr, 0, stream>>>(W2, WT + oW2, 512, 128);
    bcat_kernel<<<dim3(1), thr, 0, stream>>>(bk, bv, bkv);

    // ---- fused k|v projection (N=256) + q projection ----
    mgemm<64, 1, 0><<<dim3(2, 512), thr, 0, stream>>>(x,        1152, WT + oWkv, bkv, kvb, 256, 1024);
    mgemm<64, 1, 0><<<dim3(1, 512), thr, 0, stream>>>(x + 1024, 1152, WT + oWq,  bq,  qb,  128, 128);
    // ---- attention ----
    scores_kernel <<<dim3(2, 4, 128), thr, 0, stream>>>(qb, kvb, Sbuf);
    softmax_kernel<<<dim3(MM / 4),    thr, 0, stream>>>(Sbuf);
    pv_kernel     <<<dim3(4, 128),    thr, 0, stream>>>(Sbuf, kvb, ctxb);
    // ---- ca16 = ctx @ Wo + bo -> fp16 ----
    mgemm<128, 0, 2><<<dim3(8, 256), thr, 0, stream>>>(ctxb, 128, WT + oWo, bo, ca16, 1024, 128);
    // ---- h16 = LN(fv + ca16) -> fp16 ----
    resln_kernel<<<dim3(MM), thr, 0, stream>>>(x, ca16, h16, lng, lnb);
    // ---- hf = gelu(h @ W1 + b1) -> fp16 ----
    mgemm<128, 0, 1><<<dim3(4, 256), thr, 0, stream>>>(h16, 1024, WT + oW1, b1, hf, 512, 1024);
    // ---- h2 = hf @ W2 + b2 -> fp32 ----
    mgemm<64, 0, 0><<<dim3(1, 512), thr, 0, stream>>>(hf, 512, WT + oW2, b2, h2, 128, 512);
    // ---- conv + sigmoid ----
    conv_kernel<<<dim3(4, 128), thr, 0, stream>>>(h2, Wc, bc, out);
}